// Round 2
// baseline (158.274 us; speedup 1.0000x reference)
//
#include <hip/hip_runtime.h>

// Problem constants: B=8, N=16384, S=1024, T=2, D=3
#define NPTS 16384
#define SPTS 1024

typedef _Float16 half8 __attribute__((ext_vector_type(8)));
typedef float float16 __attribute__((ext_vector_type(16)));

union H8 { _Float16 h[8]; half8 v; uint4 q4; };

// min across each 32-lane half (validated r6/r7, absmax 0)
__device__ inline float wave32_min(float v) {
    v = fminf(v, __int_as_float(__builtin_amdgcn_mov_dpp(__float_as_int(v), 0xB1, 0xF, 0xF, true)));
    v = fminf(v, __int_as_float(__builtin_amdgcn_mov_dpp(__float_as_int(v), 0x4E, 0xF, 0xF, true)));
    v = fminf(v, __int_as_float(__builtin_amdgcn_mov_dpp(__float_as_int(v), 0x141, 0xF, 0xF, true)));
    v = fminf(v, __int_as_float(__builtin_amdgcn_mov_dpp(__float_as_int(v), 0x140, 0xF, 0xF, true)));
    v = fminf(v, __int_as_float(__builtin_amdgcn_ds_swizzle(__float_as_int(v), 0x401F)));
    return v;
}

// 3-way min written so LLVM's performMinMaxCombine can fuse to v_min3_f32.
// NO inline asm: r9 used asm min3 reading MFMA dest regs directly and failed
// with nondeterministic absmax ~400-468 (suspected MFMA->VALU hazard not
// inserted for inline-asm consumers). Builtin dataflow keeps hazards correct.
__device__ inline float min3f(float a, float b, float c) {
    return fminf(fminf(a, b), c);
}

// D[m][n] = A(gt)[m]·B(sp)[n], A=[x,y,z,|q|^2,1,0..], B=[-2x',-2y',-2z',1,|p'|^2,0..]
// One 32x32x16 f16 MFMA = 1024 exact sq-distances (fp32 accumulate; validated r6/r7).
// Frag LDS: per 32-point tile, 33 uint4 (32 lanes*16B + zero slot for lanes 32..63).
// C layout: col=lane&31, row=(reg&3)+8*(reg>>2)+4*(lane>>5).
// NOTE (r8 lesson): register ceiling is binding. (256,3) -> cap 170, no spill.
// (256,4) -> cap 128 + scratch spill -> 13.5 GB traffic, 45x slower.
// r10: paired t-iterations (2 MFMAs in flight) + min chains shaped for min3
// fusion. Exact same values as verified baseline (min is associative).

__global__ __launch_bounds__(256, 3) void fused_kernel(
    const float* __restrict__ gt,   // [8,16384,3]
    const float* __restrict__ sp,   // [8,1024,3]
    const float* __restrict__ tgt,  // [16,16384,3]
    const float* __restrict__ tsp,  // [16,1024,3]
    const float* __restrict__ tm,   // [2,3,3]
    float* __restrict__ accum,
    unsigned int* __restrict__ minarr,  // fallback path
    float* __restrict__ slab,           // [24][32][1024] per-block col-mins
    int use_slab)
{
    const int bid = blockIdx.x;
    const int tid = threadIdx.x;
    const int lane = tid & 63;
    const int lh = lane & 31;
    const int w = tid >> 6;  // wave 0..3

    __shared__ uint4 s_frag4[1584];  // sp frags [0,1056) + gt frags [1056,1584) = 25.3 KB

    if (bid >= 768) {
        // ---------------- consistency MSE (fp32 exact), tail blocks ----------------
        int idx = (bid - 768) * 256 + tid;  // over (t,b,s) = 2*8*1024
        int t = idx >> 13;
        int bs = idx & 8191;
        const float* p = sp + (size_t)bs * 3;
        float x = p[0], y = p[1], z = p[2];
        const float* m = tm + t * 9;
        const float* q = tsp + (size_t)idx * 3;
        float acc = 0.f;
#pragma unroll
        for (int e = 0; e < 3; e++) {
            float v = fmaf(x, m[e], fmaf(y, m[3 + e], z * m[6 + e]));
            float d = v - q[e];
            acc = fmaf(d, d, acc);
        }
        for (int o = 32; o > 0; o >>= 1) acc += __shfl_down(acc, o, 64);
        if ((tid & 63) == 0)
            atomicAdd(accum, acc * (1000.f / (2.f * 8.f * 1024.f * 3.f)));
        return;
    }

    // ---------------- fused chamfer: one D matrix, both mins ----------------
    int bb = bid >> 5;         // 24 batches
    int mc = bid & 31;         // 512-row gt chunk
    const float* spp = (bb < 8) ? sp + (size_t)bb * SPTS * 3
                                : tsp + (size_t)(bb - 8) * SPTS * 3;
    const float* qp  = (bb < 8) ? gt + (size_t)bb * NPTS * 3
                                : tgt + (size_t)(bb - 8) * NPTS * 3;

    // zero slots for all 48 tiles (32 sp + 16 gt): index t*33+32
    if (tid < 48) s_frag4[tid * 33 + 32] = make_uint4(0, 0, 0, 0);
    // stage sp B-frags (1024 points)
    for (int i = tid; i < 1024; i += 256) {
        const float* pp = spp + (size_t)i * 3;
        float sx = pp[0], sy = pp[1], sz = pp[2];
        H8 bf; bf.q4 = make_uint4(0, 0, 0, 0);
        bf.h[0] = (_Float16)(-2.f * sx); bf.h[1] = (_Float16)(-2.f * sy);
        bf.h[2] = (_Float16)(-2.f * sz); bf.h[3] = (_Float16)1.f;
        bf.h[4] = (_Float16)(sx * sx + sy * sy + sz * sz);
        s_frag4[(i >> 5) * 33 + (i & 31)] = bf.q4;
    }
    // stage gt A-frags (512 points of this chunk)
    for (int i = tid; i < 512; i += 256) {
        const float* pp = qp + (size_t)(mc * 512 + i) * 3;
        float x = pp[0], y = pp[1], z = pp[2];
        H8 af; af.q4 = make_uint4(0, 0, 0, 0);
        af.h[0] = (_Float16)x; af.h[1] = (_Float16)y; af.h[2] = (_Float16)z;
        af.h[3] = (_Float16)(x * x + y * y + z * z); af.h[4] = (_Float16)1.f;
        s_frag4[1056 + (i >> 5) * 33 + (i & 31)] = af.q4;
    }
    __syncthreads();

    const char* lds = (const char*)s_frag4;
    const int laneoff = (lane < 32) ? lh * 16 : 512;
    const char* bBase = lds + laneoff;
    const char* aBase = lds + 1056 * 16 + laneoff;

    float16 z16 = {0.f,0.f,0.f,0.f,0.f,0.f,0.f,0.f,0.f,0.f,0.f,0.f,0.f,0.f,0.f,0.f};
    float cm[32];
#pragma unroll
    for (int t = 0; t < 32; t++) cm[t] = 1e30f;
    float wsum = 0.f;

    for (int mi = 0; mi < 4; mi++) {
        int mt = w * 4 + mi;  // this wave's m-tile (0..15)
        H8 a; a.q4 = *(const uint4*)(aBase + mt * 528);
        float rm[16];
#pragma unroll
        for (int r = 0; r < 16; r++) rm[r] = 1e30f;
#pragma unroll
        for (int t = 0; t < 32; t += 2) {
            H8 b0; b0.q4 = *(const uint4*)(bBase + t * 528);
            H8 b1; b1.q4 = *(const uint4*)(bBase + (t + 1) * 528);
            float16 d0 = __builtin_amdgcn_mfma_f32_32x32x16_f16(a.v, b0.v, z16, 0, 0, 0);
            float16 d1 = __builtin_amdgcn_mfma_f32_32x32x16_f16(a.v, b1.v, z16, 0, 0, 0);
            // row-min accumulate (gt side): min3-fusable shape
#pragma unroll
            for (int r = 0; r < 16; r++) rm[r] = min3f(rm[r], d0[r], d1[r]);
            // col-min (sp side): min3-fusable chains over this lane's 16 rows
            {
                float g0 = min3f(d0[0],  d0[1],  d0[2]);
                float g1 = min3f(d0[3],  d0[4],  d0[5]);
                float g2 = min3f(d0[6],  d0[7],  d0[8]);
                float g3 = min3f(d0[9],  d0[10], d0[11]);
                float g4 = min3f(d0[12], d0[13], d0[14]);
                float h0 = min3f(g0, g1, g2);
                float h1 = min3f(g3, g4, d0[15]);
                cm[t] = min3f(cm[t], h0, h1);
            }
            {
                float g0 = min3f(d1[0],  d1[1],  d1[2]);
                float g1 = min3f(d1[3],  d1[4],  d1[5]);
                float g2 = min3f(d1[6],  d1[7],  d1[8]);
                float g3 = min3f(d1[9],  d1[10], d1[11]);
                float g4 = min3f(d1[12], d1[13], d1[14]);
                float h0 = min3f(g0, g1, g2);
                float h1 = min3f(g3, g4, d1[15]);
                cm[t + 1] = min3f(cm[t + 1], h0, h1);
            }
        }
        float tsum = 0.f;
#pragma unroll
        for (int r = 0; r < 16; r++) tsum += wave32_min(rm[r]);
        wsum += tsum;
    }
    wsum += __shfl_xor(wsum, 32, 64);
    if (lane == 0) {
        float scale = (bb < 8) ? 1.f / (2.f * 3.f * 8.f * 16384.f)
                               : 1.f / (2.f * 3.f * 16.f * 16384.f);
        atomicAdd(accum, wsum * scale);
    }

    // ---- block-level col-min combine -> private slab (plain coalesced stores) ----
    __syncthreads();
    float* colbuf = (float*)s_frag4;  // overlay sp-frag region (4096 floats)
#pragma unroll
    for (int t = 0; t < 32; t++) {
        float v = fminf(cm[t], __shfl_xor(cm[t], 32, 64));  // merge row-halves
        if (lane < 32) colbuf[(w * 32 + t) * 32 + lh] = v;
    }
    __syncthreads();
#pragma unroll
    for (int k = 0; k < 4; k++) {
        int e = k * 256 + tid;  // e = t*32 + col
        int t = e >> 5, col = e & 31;
        float v = fminf(fminf(colbuf[(0 * 32 + t) * 32 + col], colbuf[(1 * 32 + t) * 32 + col]),
                        fminf(colbuf[(2 * 32 + t) * 32 + col], colbuf[(3 * 32 + t) * 32 + col]));
        if (use_slab)
            slab[((size_t)(bb * 32 + mc)) * 1024 + e] = v;
        else
            atomicMin(&minarr[bb * SPTS + e], __float_as_uint(fmaxf(v, 0.f)));
    }
}

// 96 blocks x 256: each thread owns one (bb,e); min over 32 slabs, scale, sum -> accum
__global__ __launch_bounds__(256) void reduce_kernel(
    const unsigned int* __restrict__ minarr,
    const float* __restrict__ slab,
    float* __restrict__ accum,
    int use_slab)
{
    int eg = blockIdx.x * 256 + threadIdx.x;  // 0..24575
    int bb = eg >> 10, e = eg & 1023;
    float v;
    if (use_slab) {
        v = 1e30f;
#pragma unroll 8
        for (int k = 0; k < 32; k++)
            v = fminf(v, slab[((size_t)(bb * 32 + k)) * 1024 + e]);
    } else {
        v = __uint_as_float(minarr[eg]);
    }
    float scale = (bb < 8) ? 1.f / (2.f * 3.f * 8.f * 1024.f)
                           : 1.f / (2.f * 3.f * 16.f * 1024.f);
    float s = v * scale;
    for (int o = 32; o > 0; o >>= 1) s += __shfl_down(s, o, 64);
    if ((threadIdx.x & 63) == 0) atomicAdd(accum, s);
}

__global__ void out_kernel(const float* __restrict__ accum, float* __restrict__ out)
{
    if (threadIdx.x == 0) out[0] = accum[0];
}

extern "C" void kernel_launch(void* const* d_in, const int* in_sizes, int n_in,
                              void* d_out, int out_size, void* d_ws, size_t ws_size,
                              hipStream_t stream) {
    const float* gt  = (const float*)d_in[0];  // gt_points [8,16384,3]
    const float* sp  = (const float*)d_in[1];  // structure_points [8,1024,3]
    const float* tgt = (const float*)d_in[2];  // transed_gt_points [2,8,16384,3]
    const float* tsp = (const float*)d_in[3];  // transed_structure_points [2,8,1024,3]
    const float* tm  = (const float*)d_in[4];  // trans_mats [2,3,3]
    float* out = (float*)d_out;

    float* accum = (float*)d_ws;
    unsigned int* minarr = (unsigned int*)((char*)d_ws + 64);
    size_t slab_off = 64 + (size_t)24 * 1024 * 4;
    float* slab = (float*)((char*)d_ws + slab_off);
    size_t need = slab_off + (size_t)24 * 32 * 1024 * 4;
    int use_slab = (ws_size >= need) ? 1 : 0;  // constant across calls (graph-safe)

    hipMemsetAsync(accum, 0, 64, stream);
    if (!use_slab)
        hipMemsetAsync(minarr, 0x7F, 24 * 1024 * sizeof(unsigned int), stream);

    fused_kernel<<<832, 256, 0, stream>>>(gt, sp, tgt, tsp, tm, accum, minarr, slab, use_slab);
    reduce_kernel<<<96, 256, 0, stream>>>(minarr, slab, accum, use_slab);
    out_kernel<<<1, 64, 0, stream>>>(accum, out);
}

// Round 3
// 135.403 us; speedup vs baseline: 1.1689x; 1.1689x over previous
//
#include <hip/hip_runtime.h>

// Problem constants: B=8, N=16384, S=1024, T=2, D=3
#define NPTS 16384
#define SPTS 1024

typedef _Float16 half8 __attribute__((ext_vector_type(8)));
typedef float float16 __attribute__((ext_vector_type(16)));

union H8 { _Float16 h[8]; half8 v; uint4 q4; };

// min across each 32-lane half (validated r6/r7, absmax 0)
__device__ inline float wave32_min(float v) {
    v = fminf(v, __int_as_float(__builtin_amdgcn_mov_dpp(__float_as_int(v), 0xB1, 0xF, 0xF, true)));
    v = fminf(v, __int_as_float(__builtin_amdgcn_mov_dpp(__float_as_int(v), 0x4E, 0xF, 0xF, true)));
    v = fminf(v, __int_as_float(__builtin_amdgcn_mov_dpp(__float_as_int(v), 0x141, 0xF, 0xF, true)));
    v = fminf(v, __int_as_float(__builtin_amdgcn_mov_dpp(__float_as_int(v), 0x140, 0xF, 0xF, true)));
    v = fminf(v, __int_as_float(__builtin_amdgcn_ds_swizzle(__float_as_int(v), 0x401F)));
    return v;
}

// 3-way min shaped for LLVM's v_min3_f32 fusion (no inline asm: r9 hazard lesson).
__device__ inline float min3f(float a, float b, float c) {
    return fminf(fminf(a, b), c);
}

// Workspace layout (floats unless noted):
//  [0]        counter-adjacent scratch (zeroed by 64B memset)
//  [1]        unsigned completion counter (zeroed by same memset)
//  [16..848)  partials[832]  — per-fused-block sums, plain stores (no init needed)
//  [1024..1120) rsum[96]     — per-reduce-block sums, plain stores
//  byte 8192  minarr[24576]u — atomic fallback only (needs 0x7F memset)
//  byte 106496 slab: fp32 [24][32][1024] (3.0MB) or fp16 (1.5MB)
// mode: 2=fp32 slab, 1=fp16 slab, 0=atomicMin fallback. Constant per ws_size.
#define SLAB_OFF 106496
#define NEED32 3252224
#define NEED16 1679360

// r11: (a) 5 ops -> 3: partials replace atomicAdd-to-accum; reduce+out merged via
// last-block counter. (b) fp16 slab tier (1.68MB) so plain-store col-min path can
// engage (r10 counters: 47MB WRITE_SIZE = 786K atomicMin write-through; slab didn't
// fit 3.24MB). (c) 4-deep MFMA in-flight (r10: MfmaUtil 13% / VALUBusy 44% /
// Occ 43% = latency-bound, not throughput-bound).
// r8 lesson stands: (256,3) -> 170 VGPR cap; estimate ~125 here, no spill.

__global__ __launch_bounds__(256, 3) void fused_kernel(
    const float* __restrict__ gt,   // [8,16384,3]
    const float* __restrict__ sp,   // [8,1024,3]
    const float* __restrict__ tgt,  // [16,16384,3]
    const float* __restrict__ tsp,  // [16,1024,3]
    const float* __restrict__ tm,   // [2,3,3]
    float* __restrict__ partials,   // [832]
    unsigned int* __restrict__ minarr,
    float* __restrict__ slab32,
    _Float16* __restrict__ slab16,
    int mode)
{
    const int bid = blockIdx.x;
    const int tid = threadIdx.x;
    const int lane = tid & 63;
    const int lh = lane & 31;
    const int w = tid >> 6;  // wave 0..3

    __shared__ uint4 s_frag4[1584];  // sp frags [0,1056) + gt frags [1056,1584) = 25.3 KB
    __shared__ float wpart[4];

    if (bid >= 768) {
        // ---------------- consistency MSE (fp32 exact), tail blocks ----------------
        int idx = (bid - 768) * 256 + tid;  // over (t,b,s) = 2*8*1024
        int t = idx >> 13;
        int bs = idx & 8191;
        const float* p = sp + (size_t)bs * 3;
        float x = p[0], y = p[1], z = p[2];
        const float* m = tm + t * 9;
        const float* q = tsp + (size_t)idx * 3;
        float acc = 0.f;
#pragma unroll
        for (int e = 0; e < 3; e++) {
            float v = fmaf(x, m[e], fmaf(y, m[3 + e], z * m[6 + e]));
            float d = v - q[e];
            acc = fmaf(d, d, acc);
        }
        for (int o = 32; o > 0; o >>= 1) acc += __shfl_down(acc, o, 64);
        if (lane == 0) wpart[w] = acc;
        __syncthreads();
        if (tid == 0)
            partials[bid] = (wpart[0] + wpart[1] + wpart[2] + wpart[3])
                            * (1000.f / (2.f * 8.f * 1024.f * 3.f));
        return;
    }

    // ---------------- fused chamfer: one D matrix, both mins ----------------
    int bb = bid >> 5;         // 24 batches
    int mc = bid & 31;         // 512-row gt chunk
    const float* spp = (bb < 8) ? sp + (size_t)bb * SPTS * 3
                                : tsp + (size_t)(bb - 8) * SPTS * 3;
    const float* qp  = (bb < 8) ? gt + (size_t)bb * NPTS * 3
                                : tgt + (size_t)(bb - 8) * NPTS * 3;

    // zero slots for all 48 tiles (32 sp + 16 gt): index t*33+32
    if (tid < 48) s_frag4[tid * 33 + 32] = make_uint4(0, 0, 0, 0);
    // stage sp B-frags (1024 points)
    for (int i = tid; i < 1024; i += 256) {
        const float* pp = spp + (size_t)i * 3;
        float sx = pp[0], sy = pp[1], sz = pp[2];
        H8 bf; bf.q4 = make_uint4(0, 0, 0, 0);
        bf.h[0] = (_Float16)(-2.f * sx); bf.h[1] = (_Float16)(-2.f * sy);
        bf.h[2] = (_Float16)(-2.f * sz); bf.h[3] = (_Float16)1.f;
        bf.h[4] = (_Float16)(sx * sx + sy * sy + sz * sz);
        s_frag4[(i >> 5) * 33 + (i & 31)] = bf.q4;
    }
    // stage gt A-frags (512 points of this chunk)
    for (int i = tid; i < 512; i += 256) {
        const float* pp = qp + (size_t)(mc * 512 + i) * 3;
        float x = pp[0], y = pp[1], z = pp[2];
        H8 af; af.q4 = make_uint4(0, 0, 0, 0);
        af.h[0] = (_Float16)x; af.h[1] = (_Float16)y; af.h[2] = (_Float16)z;
        af.h[3] = (_Float16)(x * x + y * y + z * z); af.h[4] = (_Float16)1.f;
        s_frag4[1056 + (i >> 5) * 33 + (i & 31)] = af.q4;
    }
    __syncthreads();

    const char* lds = (const char*)s_frag4;
    const int laneoff = (lane < 32) ? lh * 16 : 512;
    const char* bBase = lds + laneoff;
    const char* aBase = lds + 1056 * 16 + laneoff;

    float16 z16 = {0.f,0.f,0.f,0.f,0.f,0.f,0.f,0.f,0.f,0.f,0.f,0.f,0.f,0.f,0.f,0.f};
    float cm[32];
#pragma unroll
    for (int t = 0; t < 32; t++) cm[t] = 1e30f;
    float wsum = 0.f;

    for (int mi = 0; mi < 4; mi++) {
        int mt = w * 4 + mi;  // this wave's m-tile (0..15)
        H8 a; a.q4 = *(const uint4*)(aBase + mt * 528);
        float rm[16];
#pragma unroll
        for (int r = 0; r < 16; r++) rm[r] = 1e30f;
#pragma unroll
        for (int t = 0; t < 32; t += 4) {
            H8 b0; b0.q4 = *(const uint4*)(bBase + t * 528);
            H8 b1; b1.q4 = *(const uint4*)(bBase + (t + 1) * 528);
            H8 b2; b2.q4 = *(const uint4*)(bBase + (t + 2) * 528);
            H8 b3; b3.q4 = *(const uint4*)(bBase + (t + 3) * 528);
            float16 d0 = __builtin_amdgcn_mfma_f32_32x32x16_f16(a.v, b0.v, z16, 0, 0, 0);
            float16 d1 = __builtin_amdgcn_mfma_f32_32x32x16_f16(a.v, b1.v, z16, 0, 0, 0);
            float16 d2 = __builtin_amdgcn_mfma_f32_32x32x16_f16(a.v, b2.v, z16, 0, 0, 0);
            float16 d3 = __builtin_amdgcn_mfma_f32_32x32x16_f16(a.v, b3.v, z16, 0, 0, 0);
            // row-min accumulate (gt side): 2 min3 per r fold 4 tiles
#pragma unroll
            for (int r = 0; r < 16; r++) {
                float x = min3f(d0[r], d1[r], d2[r]);
                rm[r] = min3f(rm[r], x, d3[r]);
            }
            // col-min (sp side): 8-op min3 chain per tile over this lane's 16 rows
            {
                float g0 = min3f(d0[0],  d0[1],  d0[2]);
                float g1 = min3f(d0[3],  d0[4],  d0[5]);
                float g2 = min3f(d0[6],  d0[7],  d0[8]);
                float g3 = min3f(d0[9],  d0[10], d0[11]);
                float g4 = min3f(d0[12], d0[13], d0[14]);
                cm[t] = min3f(cm[t], min3f(g0, g1, g2), min3f(g3, g4, d0[15]));
            }
            {
                float g0 = min3f(d1[0],  d1[1],  d1[2]);
                float g1 = min3f(d1[3],  d1[4],  d1[5]);
                float g2 = min3f(d1[6],  d1[7],  d1[8]);
                float g3 = min3f(d1[9],  d1[10], d1[11]);
                float g4 = min3f(d1[12], d1[13], d1[14]);
                cm[t + 1] = min3f(cm[t + 1], min3f(g0, g1, g2), min3f(g3, g4, d1[15]));
            }
            {
                float g0 = min3f(d2[0],  d2[1],  d2[2]);
                float g1 = min3f(d2[3],  d2[4],  d2[5]);
                float g2 = min3f(d2[6],  d2[7],  d2[8]);
                float g3 = min3f(d2[9],  d2[10], d2[11]);
                float g4 = min3f(d2[12], d2[13], d2[14]);
                cm[t + 2] = min3f(cm[t + 2], min3f(g0, g1, g2), min3f(g3, g4, d2[15]));
            }
            {
                float g0 = min3f(d3[0],  d3[1],  d3[2]);
                float g1 = min3f(d3[3],  d3[4],  d3[5]);
                float g2 = min3f(d3[6],  d3[7],  d3[8]);
                float g3 = min3f(d3[9],  d3[10], d3[11]);
                float g4 = min3f(d3[12], d3[13], d3[14]);
                cm[t + 3] = min3f(cm[t + 3], min3f(g0, g1, g2), min3f(g3, g4, d3[15]));
            }
        }
        float tsum = 0.f;
#pragma unroll
        for (int r = 0; r < 16; r++) tsum += wave32_min(rm[r]);
        wsum += tsum;
    }
    wsum += __shfl_xor(wsum, 32, 64);
    if (lane == 0) wpart[w] = wsum;

    // ---- block-level col-min combine -> slab (plain stores) or atomic fallback ----
    __syncthreads();
    if (tid == 0) {
        float scale = (bb < 8) ? 1.f / (2.f * 3.f * 8.f * 16384.f)
                               : 1.f / (2.f * 3.f * 16.f * 16384.f);
        partials[bid] = (wpart[0] + wpart[1] + wpart[2] + wpart[3]) * scale;
    }
    float* colbuf = (float*)s_frag4;  // overlay sp-frag region (4096 floats)
#pragma unroll
    for (int t = 0; t < 32; t++) {
        float v = fminf(cm[t], __shfl_xor(cm[t], 32, 64));  // merge row-halves
        if (lane < 32) colbuf[(w * 32 + t) * 32 + lh] = v;
    }
    __syncthreads();
#pragma unroll
    for (int k = 0; k < 4; k++) {
        int e = k * 256 + tid;  // e = t*32 + col
        int t = e >> 5, col = e & 31;
        float v = fminf(fminf(colbuf[(0 * 32 + t) * 32 + col], colbuf[(1 * 32 + t) * 32 + col]),
                        fminf(colbuf[(2 * 32 + t) * 32 + col], colbuf[(3 * 32 + t) * 32 + col]));
        size_t si = ((size_t)(bb * 32 + mc)) * 1024 + e;
        if (mode == 2)      slab32[si] = v;
        else if (mode == 1) slab16[si] = (_Float16)v;
        else                atomicMin(&minarr[bb * SPTS + e], __float_as_uint(fmaxf(v, 0.f)));
    }
}

// 96 blocks x 256: col-min finalize + grand total via last-block counter.
__global__ __launch_bounds__(256) void reduce_out_kernel(
    const unsigned int* __restrict__ minarr,
    const float* __restrict__ slab32,
    const _Float16* __restrict__ slab16,
    const float* __restrict__ partials,  // [832]
    float* __restrict__ rsum,            // [96]
    unsigned int* __restrict__ counter,
    float* __restrict__ out,
    int mode)
{
    const int tid = threadIdx.x;
    int eg = blockIdx.x * 256 + tid;  // 0..24575
    int bb = eg >> 10, e = eg & 1023;
    float v;
    if (mode == 2) {
        v = 1e30f;
#pragma unroll 8
        for (int k = 0; k < 32; k++)
            v = fminf(v, slab32[((size_t)(bb * 32 + k)) * 1024 + e]);
    } else if (mode == 1) {
        v = 1e30f;
#pragma unroll 8
        for (int k = 0; k < 32; k++)
            v = fminf(v, (float)slab16[((size_t)(bb * 32 + k)) * 1024 + e]);
    } else {
        v = __uint_as_float(minarr[eg]);
    }
    float scale = (bb < 8) ? 1.f / (2.f * 3.f * 8.f * 1024.f)
                           : 1.f / (2.f * 3.f * 16.f * 1024.f);
    float s = v * scale;
    for (int o = 32; o > 0; o >>= 1) s += __shfl_down(s, o, 64);

    __shared__ float bsum[4];
    __shared__ int lastFlag;
    if ((tid & 63) == 0) bsum[tid >> 6] = s;
    __syncthreads();
    if (tid == 0) {
        rsum[blockIdx.x] = bsum[0] + bsum[1] + bsum[2] + bsum[3];
        __threadfence();
        unsigned int old = atomicAdd(counter, 1u);
        lastFlag = (old == 95u);
    }
    __syncthreads();
    if (lastFlag) {
        __threadfence();
        float s2 = 0.f;
        for (int i = tid; i < 96 + 832; i += 256)
            s2 += (i < 96) ? rsum[i] : partials[i - 96];
        for (int o = 32; o > 0; o >>= 1) s2 += __shfl_down(s2, o, 64);
        if ((tid & 63) == 0) bsum[tid >> 6] = s2;
        __syncthreads();
        if (tid == 0) out[0] = bsum[0] + bsum[1] + bsum[2] + bsum[3];
    }
}

extern "C" void kernel_launch(void* const* d_in, const int* in_sizes, int n_in,
                              void* d_out, int out_size, void* d_ws, size_t ws_size,
                              hipStream_t stream) {
    const float* gt  = (const float*)d_in[0];  // gt_points [8,16384,3]
    const float* sp  = (const float*)d_in[1];  // structure_points [8,1024,3]
    const float* tgt = (const float*)d_in[2];  // transed_gt_points [2,8,16384,3]
    const float* tsp = (const float*)d_in[3];  // transed_structure_points [2,8,1024,3]
    const float* tm  = (const float*)d_in[4];  // trans_mats [2,3,3]
    float* out = (float*)d_out;

    float* wsf = (float*)d_ws;
    unsigned int* counter = (unsigned int*)(wsf + 1);
    float* partials = wsf + 16;    // 832 floats
    float* rsum = wsf + 1024;      // 96 floats
    unsigned int* minarr = (unsigned int*)((char*)d_ws + 8192);   // 24576 u32
    float* slab32 = (float*)((char*)d_ws + SLAB_OFF);
    _Float16* slab16 = (_Float16*)((char*)d_ws + SLAB_OFF);

    int mode = (ws_size >= NEED32) ? 2 : ((ws_size >= NEED16) ? 1 : 0);

    hipMemsetAsync(d_ws, 0, 64, stream);  // counter (+scratch)
    if (mode == 0)
        hipMemsetAsync(minarr, 0x7F, 24 * 1024 * sizeof(unsigned int), stream);

    fused_kernel<<<832, 256, 0, stream>>>(gt, sp, tgt, tsp, tm, partials, minarr,
                                          slab32, slab16, mode);
    reduce_out_kernel<<<96, 256, 0, stream>>>(minarr, slab32, slab16, partials,
                                              rsum, counter, out, mode);
}